// Round 5
// baseline (255.908 us; speedup 1.0000x reference)
//
#include <hip/hip_runtime.h>

// B=16, S=8192, D=256, N=64, IDX=3, slot-norm softmax.
// logits = (x·Q' + qb)/16 with Q' = queries@Wk;  out = (wsum·Wv^T)/denom + bv
// wsum[b,:] = sum_s p3[b,s]·x[b,s,:], denom[b] = sum_s p3[b,s].
// v5: v4 structure (barrier-free wave-private slabs, both MFMA operands in LDS)
// with: dynamic i-loop (pf[16] forced live -> real prefetch), no-max softmax
// (logits bounded, masked -> exact 0; shfl chain 8->5), per-group dacc.

#define B_ 16
#define S_ 8192
#define D_ 256
#define N_ 64
#define LSTR 264  // slab row stride in bf16 elems (16B-aligned, bank-even)

typedef __attribute__((ext_vector_type(8))) short s8_t;   // 8 bf16 MFMA frag
typedef __attribute__((ext_vector_type(4))) float f4_t;   // 4 fp32 MFMA acc
typedef unsigned int u32;
typedef unsigned short u16;

__device__ __forceinline__ u16 f2bf(float f) {
  u32 u = __builtin_bit_cast(u32, f);
  u += 0x7fffu + ((u >> 16) & 1u);   // RNE
  return (u16)(u >> 16);
}
__device__ __forceinline__ float bflo(u32 p) { return __builtin_bit_cast(float, p << 16); }
__device__ __forceinline__ float bfhi(u32 p) { return __builtin_bit_cast(float, p & 0xffff0000u); }

// ---- prep: Q' = queries@Wk -> bf16 FRAG-ORDERED for MFMA B-operand; qb[n]=q·bk ----
__global__ void prep_qk(const float* __restrict__ queries, const float* __restrict__ Wk,
                        const float* __restrict__ bk, u16* __restrict__ qf,
                        float* __restrict__ qb) {
  __shared__ float ql[D_];
  __shared__ float rb[D_];
  const int n = blockIdx.x, d = threadIdx.x;
  const float qv = queries[n * D_ + d];
  ql[d] = qv;
  rb[d] = qv * bk[d];
  __syncthreads();
  float a0 = 0.f, a1 = 0.f, a2 = 0.f, a3 = 0.f;
#pragma unroll 4
  for (int e = 0; e < D_; e += 4) {
    a0 = fmaf(ql[e + 0], Wk[(e + 0) * D_ + d], a0);
    a1 = fmaf(ql[e + 1], Wk[(e + 1) * D_ + d], a1);
    a2 = fmaf(ql[e + 2], Wk[(e + 2) * D_ + d], a2);
    a3 = fmaf(ql[e + 3], Wk[(e + 3) * D_ + d], a3);
  }
  const float acc = (a0 + a1) + (a2 + a3);
  // frag elem j of frag (t4,c,lane=g*16+c15) = Q'[16t4+c15][32c+8g+j]
  const int t4 = n >> 4, c15 = n & 15, c = d >> 5, g = (d >> 3) & 3, j = d & 7;
  qf[((t4 * 8 + c) * 64 + g * 16 + c15) * 8 + j] = f2bf(acc);
  for (int s = 128; s > 0; s >>= 1) { __syncthreads(); if (d < s) rb[d] += rb[d + s]; }
  if (d == 0) qb[n] = rb[0];
}

// ---- main: 512 blocks (2/CU), 256 s per block, 1 prologue barrier ----
__global__ __launch_bounds__(256, 2) void attn_main(
    const float* __restrict__ x, const int* __restrict__ mask,
    const u16* __restrict__ qf, const float* __restrict__ qb,
    float* __restrict__ pw, float* __restrict__ dpart, float* __restrict__ att) {
  __shared__ __align__(16) u16 q_lds[16384];        // 32KB Q' frag-ordered
  __shared__ __align__(16) u16 slab[4][16 * LSTR];  // 33KB wave-private x slabs
  __shared__ u32 pmL[4 * 256];                      // 4KB mask bits [np][sl]

  const int t = threadIdx.x;
  const int lane = t & 63;
  const int w = t >> 6;
  const int c15 = lane & 15;
  const int g = lane >> 4;
  const int b = blockIdx.y;
  const int sb = blockIdx.x;
  const int s0 = sb * 256;

  // stage Q' (linear copy, frag order already matches readers)
#pragma unroll
  for (int i = 0; i < 8; ++i)
    ((uint4*)q_lds)[t + 256 * i] = ((const uint4*)qf)[t + 256 * i];

  // stage mask bits for all 256 s (coalesced 256B per wave-instr)
  {
    const int np = t >> 6, s = t & 63;
#pragma unroll
    for (int q = 0; q < 4; ++q) {
      const int* mrow = mask + ((long)b * N_ + np * 16) * S_ + s0 + q * 64 + s;
      u32 bits = 0;
#pragma unroll
      for (int i = 0; i < 16; ++i) bits |= (u32)(mrow[i * S_] != 0) << i;
      pmL[np * 256 + q * 64 + s] = bits;
    }
  }

  const float qbv0 = qb[c15], qbv1 = qb[16 + c15], qbv2 = qb[32 + c15], qbv3 = qb[48 + c15];
  u16* myslab = slab[w];
  const float4* x4 = (const float4*)x;
  const long xbase = ((long)b * S_ + s0 + 16 * w) * 64 + lane;  // float4 units

  f4_t wacc = {0.f, 0.f, 0.f, 0.f};  // lane owns cols lane*4..+3
  float dacc = 0.f;                  // per-group row-sum (reduced over g at end)

  // prefetch iter 0 rows into regs
  float4 pf[16];
#pragma unroll
  for (int r = 0; r < 16; ++r) pf[r] = x4[xbase + (long)r * 64];

  __syncthreads();  // q_lds + pmL ready (slabs are wave-private, never synced)

#pragma unroll 1   // dynamic loop: pf[] must stay live across backedge => real prefetch
  for (int i = 0; i < 4; ++i) {
    // commit prefetched rows to this wave's slab (bank-even b64 writes)
#pragma unroll
    for (int r = 0; r < 16; ++r) {
      uint2 h;
      h.x = (u32)f2bf(pf[r].x) | ((u32)f2bf(pf[r].y) << 16);
      h.y = (u32)f2bf(pf[r].z) | ((u32)f2bf(pf[r].w) << 16);
      *(uint2*)&myslab[r * LSTR + lane * 4] = h;
    }
    // always-prefetch next tile (clamped; branch-free body)
    const long nbase = xbase + (long)((i < 3 ? i + 1 : 3) * 64) * 64;
#pragma unroll
    for (int r = 0; r < 16; ++r) pf[r] = x4[nbase + (long)r * 64];

    // logits: A from own slab, B from q_lds (all ds_read_b128, <=2-way = free)
    const u16* arow = &myslab[c15 * LSTR + g * 8];
    f4_t acc0 = {0.f,0.f,0.f,0.f}, acc1 = {0.f,0.f,0.f,0.f};
    f4_t acc2 = {0.f,0.f,0.f,0.f}, acc3 = {0.f,0.f,0.f,0.f};
#pragma unroll
    for (int c = 0; c < 8; ++c) {
      const s8_t a  = *(const s8_t*)&arow[c * 32];
      acc0 = __builtin_amdgcn_mfma_f32_16x16x32_bf16(a, *(const s8_t*)&q_lds[((0 * 8 + c) * 64 + lane) * 8], acc0, 0, 0, 0);
      acc1 = __builtin_amdgcn_mfma_f32_16x16x32_bf16(a, *(const s8_t*)&q_lds[((1 * 8 + c) * 64 + lane) * 8], acc1, 0, 0, 0);
      acc2 = __builtin_amdgcn_mfma_f32_16x16x32_bf16(a, *(const s8_t*)&q_lds[((2 * 8 + c) * 64 + lane) * 8], acc2, 0, 0, 0);
      acc3 = __builtin_amdgcn_mfma_f32_16x16x32_bf16(a, *(const s8_t*)&q_lds[((3 * 8 + c) * 64 + lane) * 8], acc3, 0, 0, 0);
    }

    // no-max softmax over n=64 (logits bounded ~|0.1|; masked -> exact 0)
    // C-layout: col=c15 (n within t4), row=g*4+r
    float unorm[4];
#pragma unroll
    for (int r = 0; r < 4; ++r) {
      const int sl = i * 64 + 16 * w + g * 4 + r;
      const u32 m0 = pmL[0 * 256 + sl], m1 = pmL[1 * 256 + sl];
      const u32 m2 = pmL[2 * 256 + sl], m3 = pmL[3 * 256 + sl];
      const float e0 = ((m0 >> c15) & 1) ? __expf((acc0[r] + qbv0) * 0.0625f) : 0.f;
      const float e1 = ((m1 >> c15) & 1) ? __expf((acc1[r] + qbv1) * 0.0625f) : 0.f;
      const float e2 = ((m2 >> c15) & 1) ? __expf((acc2[r] + qbv2) * 0.0625f) : 0.f;
      const float e3 = ((m3 >> c15) & 1) ? __expf((acc3[r] + qbv3) * 0.0625f) : 0.f;
      float sm = (e0 + e1) + (e2 + e3);
      sm += __shfl_xor(sm, 1);
      sm += __shfl_xor(sm, 2);
      sm += __shfl_xor(sm, 4);
      sm += __shfl_xor(sm, 8);
      const float en3 = __shfl(e0, (lane & 48) | 3);  // n=IDX=3: t4=0, c15==3
      unorm[r] = en3 / sm;
      dacc += unorm[r];  // uniform within 16-lane group; row g*4+r owned by group g
    }
    if (c15 == 3) {
      f4_t u = {unorm[0], unorm[1], unorm[2], unorm[3]};
      *(f4_t*)&att[(long)b * S_ + s0 + i * 64 + 16 * w + g * 4] = u;
    }

    // wsum over this wave's 16 rows; lane owns cols lane*4..+3
#pragma unroll
    for (int r = 0; r < 4; ++r) {
#pragma unroll
      for (int gg = 0; gg < 4; ++gg) {
        const float a_s = __shfl(unorm[r], gg * 16);  // local row gg*4+r
        const uint2 h = *(const uint2*)&myslab[(gg * 4 + r) * LSTR + lane * 4];
        wacc[0] = fmaf(a_s, bflo(h.x), wacc[0]);
        wacc[1] = fmaf(a_s, bfhi(h.x), wacc[1]);
        wacc[2] = fmaf(a_s, bflo(h.y), wacc[2]);
        wacc[3] = fmaf(a_s, bfhi(h.y), wacc[3]);
      }
    }
  }

  // finish dacc: sum the 4 group values -> uniform across wave
  dacc += __shfl_xor(dacc, 16);
  dacc += __shfl_xor(dacc, 32);

  // block combine (slabs dead -> overlay), single end barrier pair
  __syncthreads();
  float* ldsW = (float*)slab;  // 257 floats
  if (t < 256) ldsW[t] = 0.f;
  if (t == 0) ldsW[256] = 0.f;
  __syncthreads();
#pragma unroll
  for (int j = 0; j < 4; ++j) atomicAdd(&ldsW[lane * 4 + j], wacc[j]);
  if (lane == 0) atomicAdd(&ldsW[256], dacc);
  __syncthreads();
  const int blk = b * 32 + sb;
  pw[(long)blk * D_ + t] = ldsW[t];
  if (t == 0) dpart[blk] = ldsW[256];
}

// ---- finalize: part 0 => reduce wsum + GEMV; parts 1..32 => att renorm ----
__global__ void finalize_k(const float* __restrict__ pw, const float* __restrict__ dpart,
                           const float* __restrict__ Wv, const float* __restrict__ bv,
                           float* __restrict__ out, float* __restrict__ att) {
  __shared__ float red[32];
  __shared__ float wl[D_];
  const int b = blockIdx.x, t = threadIdx.x, part = blockIdx.y;
  if (t < 32) red[t] = dpart[b * 32 + t];
  __syncthreads();
  if (t < 16) red[t] += red[t + 16];
  __syncthreads();
  if (t < 8) red[t] += red[t + 8];
  __syncthreads();
  if (t < 4) red[t] += red[t + 4];
  __syncthreads();
  if (t < 2) red[t] += red[t + 2];
  __syncthreads();
  if (t == 0) red[0] += red[1];
  __syncthreads();
  const float dn = red[0];
  if (part == 0) {
    float s0 = 0.f, s1 = 0.f, s2 = 0.f, s3 = 0.f;
    const float* p = pw + (long)b * 32 * D_ + t;
#pragma unroll 4
    for (int sb = 0; sb < 32; sb += 4) {  // coalesced 1KB per iter
      s0 += p[(sb + 0) * D_]; s1 += p[(sb + 1) * D_];
      s2 += p[(sb + 2) * D_]; s3 += p[(sb + 3) * D_];
    }
    wl[t] = (s0 + s1) + (s2 + s3);
    __syncthreads();
    const float4* wr = (const float4*)&Wv[t * D_];
    const float4* wv = (const float4*)wl;
    float d0 = 0.f, d1 = 0.f, d2 = 0.f, d3 = 0.f;
#pragma unroll 8
    for (int e = 0; e < 64; ++e) {
      const float4 a = wv[e], w4 = wr[e];
      d0 = fmaf(a.x, w4.x, d0); d1 = fmaf(a.y, w4.y, d1);
      d2 = fmaf(a.z, w4.z, d2); d3 = fmaf(a.w, w4.w, d3);
    }
    out[b * D_ + t] = ((d0 + d1) + (d2 + d3)) / dn + bv[t];
  } else {
    const float inv = 1.0f / dn;
    att[(long)b * S_ + (part - 1) * 256 + t] *= inv;
  }
}

extern "C" void kernel_launch(void* const* d_in, const int* in_sizes, int n_in,
                              void* d_out, int out_size, void* d_ws, size_t ws_size,
                              hipStream_t stream) {
  const float* x = (const float*)d_in[0];        // [16,8192,256]
  const int* mask = (const int*)d_in[1];         // [16,64,8192]
  const float* Wv = (const float*)d_in[2];
  const float* bv = (const float*)d_in[3];
  const float* Wk = (const float*)d_in[4];
  const float* bk = (const float*)d_in[5];
  const float* queries = (const float*)d_in[6];  // [64,256]

  char* ws = (char*)d_ws;
  u16* qf = (u16*)ws;                        // [0, 32768)  frag-ordered Q' bf16
  float* qb = (float*)(ws + 32768);          // [32768, 33792)
  float* pw = (float*)(ws + 33792);          // 512 x 256 f32 partials (512KB)
  float* dpart = (float*)(ws + 33792 + 524288);  // 512 floats
  float* out = (float*)d_out;                // 16*256
  float* att = out + B_ * D_;                // 16*8192

  prep_qk<<<N_, D_, 0, stream>>>(queries, Wk, bk, qf, qb);
  attn_main<<<dim3(32, B_), 256, 0, stream>>>(x, mask, qf, qb, pw, dpart, att);
  finalize_k<<<dim3(B_, 33), 256, 0, stream>>>(pw, dpart, Wv, bv, out, att);
}

// Round 7
// 253.412 us; speedup vs baseline: 1.0099x; 1.0099x over previous
//
#include <hip/hip_runtime.h>

// B=16, S=8192, D=256, N=64, IDX=3, slot-norm softmax.
// logits = (x·Q' + qb)/16 with Q' = queries@Wk;  out = (wsum·Wv^T)/denom + bv
// wsum[b,:] = sum_s p3[b,s]·x[b,s,:], denom[b] = sum_s p3[b,s].
// v6b: occupancy over register-prefetch. Q' OUT of LDS (B-frags are 1KB lane-
// contiguous loads from 32KB qf, kept L2-resident because x/mask use
// NONTEMPORAL loads). LDS = wave-private x slabs + mask bits only (~36KB) ->
// 4 blocks/CU, 1024 blocks, 16 waves/CU. nontemporal via ext_vector f4_t
// (HIP_vector_type float4 rejected by the builtin).

#define B_ 16
#define S_ 8192
#define D_ 256
#define N_ 64
#define LSTR 264  // slab row stride in bf16 elems (16B-aligned, bank-even)

typedef __attribute__((ext_vector_type(8))) short s8_t;   // 8 bf16 MFMA frag
typedef __attribute__((ext_vector_type(4))) float f4_t;   // 4 fp32 (MFMA acc / nt loads)
typedef unsigned int u32;
typedef unsigned short u16;

__device__ __forceinline__ u16 f2bf(float f) {
  u32 u = __builtin_bit_cast(u32, f);
  u += 0x7fffu + ((u >> 16) & 1u);   // RNE
  return (u16)(u >> 16);
}
__device__ __forceinline__ float bflo(u32 p) { return __builtin_bit_cast(float, p << 16); }
__device__ __forceinline__ float bfhi(u32 p) { return __builtin_bit_cast(float, p & 0xffff0000u); }

// ---- prep: Q' = queries@Wk -> bf16 FRAG-ORDERED for MFMA B-operand; qb[n]=q·bk ----
__global__ void prep_qk(const float* __restrict__ queries, const float* __restrict__ Wk,
                        const float* __restrict__ bk, u16* __restrict__ qf,
                        float* __restrict__ qb) {
  __shared__ float ql[D_];
  __shared__ float rb[D_];
  const int n = blockIdx.x, d = threadIdx.x;
  const float qv = queries[n * D_ + d];
  ql[d] = qv;
  rb[d] = qv * bk[d];
  __syncthreads();
  float a0 = 0.f, a1 = 0.f, a2 = 0.f, a3 = 0.f;
#pragma unroll 4
  for (int e = 0; e < D_; e += 4) {
    a0 = fmaf(ql[e + 0], Wk[(e + 0) * D_ + d], a0);
    a1 = fmaf(ql[e + 1], Wk[(e + 1) * D_ + d], a1);
    a2 = fmaf(ql[e + 2], Wk[(e + 2) * D_ + d], a2);
    a3 = fmaf(ql[e + 3], Wk[(e + 3) * D_ + d], a3);
  }
  const float acc = (a0 + a1) + (a2 + a3);
  // frag elem j of frag (t4,c,lane=g*16+c15) = Q'[16t4+c15][32c+8g+j]
  const int t4 = n >> 4, c15 = n & 15, c = d >> 5, g = (d >> 3) & 3, j = d & 7;
  qf[((t4 * 8 + c) * 64 + g * 16 + c15) * 8 + j] = f2bf(acc);
  for (int s = 128; s > 0; s >>= 1) { __syncthreads(); if (d < s) rb[d] += rb[d + s]; }
  if (d == 0) qb[n] = rb[0];
}

// ---- main: 1024 blocks (4/CU), 128 s per block, 1 prologue barrier ----
__global__ __launch_bounds__(256, 4) void attn_main(
    const float* __restrict__ x, const int* __restrict__ mask,
    const u16* __restrict__ qf, const float* __restrict__ qb,
    float* __restrict__ pw, float* __restrict__ dpart, float* __restrict__ att) {
  __shared__ __align__(16) u16 slab[4][16 * LSTR];  // 33KB wave-private x slabs
  __shared__ u32 pmL[4 * 128];                      // 2KB mask bits [np][sl]

  const int t = threadIdx.x;
  const int lane = t & 63;
  const int w = t >> 6;
  const int c15 = lane & 15;
  const int g = lane >> 4;
  const int b = blockIdx.y;
  const int sb = blockIdx.x;
  const int s0 = sb * 128;

  // stage mask bits for this block's 128 s (nontemporal: read-once stream)
  {
    const int np = w, s = lane;
#pragma unroll
    for (int q = 0; q < 2; ++q) {
      const int* mrow = mask + ((long)b * N_ + np * 16) * S_ + s0 + q * 64 + s;
      u32 bits = 0;
#pragma unroll
      for (int i = 0; i < 16; ++i)
        bits |= (u32)(__builtin_nontemporal_load(&mrow[i * S_]) != 0) << i;
      pmL[np * 128 + q * 64 + s] = bits;
    }
  }

  const float qbv0 = qb[c15], qbv1 = qb[16 + c15], qbv2 = qb[32 + c15], qbv3 = qb[48 + c15];
  u16* myslab = slab[w];
  const s8_t* qfs = (const s8_t*)qf;  // B-frags: 1KB lane-contiguous, L2-resident

  f4_t wacc = {0.f, 0.f, 0.f, 0.f};  // lane owns cols lane*4..+3
  float dacc = 0.f;                  // per-group row-sum (reduced over g at end)

  __syncthreads();  // pmL ready (slabs are wave-private, never synced)

#pragma unroll
  for (int i = 0; i < 2; ++i) {
    // stage 16 rows into this wave's slab (nt loads; 1KB coalesced per instr)
#pragma unroll
    for (int r = 0; r < 16; ++r) {
      const f4_t v = __builtin_nontemporal_load(
          (const f4_t*)&x[(((long)b * S_) + s0 + i * 64 + 16 * w + r) * D_ + lane * 4]);
      uint2 h;
      h.x = (u32)f2bf(v.x) | ((u32)f2bf(v.y) << 16);
      h.y = (u32)f2bf(v.z) | ((u32)f2bf(v.w) << 16);
      *(uint2*)&myslab[r * LSTR + lane * 4] = h;
    }

    // logits: A from own slab (ds_read_b128), B from qf global (L2-hot)
    const u16* arow = &myslab[c15 * LSTR + g * 8];
    f4_t acc0 = {0.f,0.f,0.f,0.f}, acc1 = {0.f,0.f,0.f,0.f};
    f4_t acc2 = {0.f,0.f,0.f,0.f}, acc3 = {0.f,0.f,0.f,0.f};
#pragma unroll
    for (int c = 0; c < 8; ++c) {
      const s8_t a = *(const s8_t*)&arow[c * 32];
      acc0 = __builtin_amdgcn_mfma_f32_16x16x32_bf16(a, qfs[(0 * 8 + c) * 64 + lane], acc0, 0, 0, 0);
      acc1 = __builtin_amdgcn_mfma_f32_16x16x32_bf16(a, qfs[(1 * 8 + c) * 64 + lane], acc1, 0, 0, 0);
      acc2 = __builtin_amdgcn_mfma_f32_16x16x32_bf16(a, qfs[(2 * 8 + c) * 64 + lane], acc2, 0, 0, 0);
      acc3 = __builtin_amdgcn_mfma_f32_16x16x32_bf16(a, qfs[(3 * 8 + c) * 64 + lane], acc3, 0, 0, 0);
    }

    // no-max softmax over n=64 (logits bounded ~|0.1|; masked -> exact 0)
    // C-layout: col=c15 (n within t4), row=g*4+r
    float unorm[4];
#pragma unroll
    for (int r = 0; r < 4; ++r) {
      const int sl = i * 64 + 16 * w + g * 4 + r;
      const u32 m0 = pmL[0 * 128 + sl], m1 = pmL[1 * 128 + sl];
      const u32 m2 = pmL[2 * 128 + sl], m3 = pmL[3 * 128 + sl];
      const float e0 = ((m0 >> c15) & 1) ? __expf((acc0[r] + qbv0) * 0.0625f) : 0.f;
      const float e1 = ((m1 >> c15) & 1) ? __expf((acc1[r] + qbv1) * 0.0625f) : 0.f;
      const float e2 = ((m2 >> c15) & 1) ? __expf((acc2[r] + qbv2) * 0.0625f) : 0.f;
      const float e3 = ((m3 >> c15) & 1) ? __expf((acc3[r] + qbv3) * 0.0625f) : 0.f;
      float sm = (e0 + e1) + (e2 + e3);
      sm += __shfl_xor(sm, 1);
      sm += __shfl_xor(sm, 2);
      sm += __shfl_xor(sm, 4);
      sm += __shfl_xor(sm, 8);
      const float en3 = __shfl(e0, (lane & 48) | 3);  // n=IDX=3: t4=0, c15==3
      unorm[r] = en3 / sm;
      dacc += unorm[r];  // uniform within 16-lane group; row g*4+r owned by group g
    }
    if (c15 == 3) {
      f4_t u = {unorm[0], unorm[1], unorm[2], unorm[3]};
      *(f4_t*)&att[(long)b * S_ + s0 + i * 64 + 16 * w + g * 4] = u;
    }

    // wsum over this wave's 16 rows; lane owns cols lane*4..+3
#pragma unroll
    for (int r = 0; r < 4; ++r) {
#pragma unroll
      for (int gg = 0; gg < 4; ++gg) {
        const float a_s = __shfl(unorm[r], gg * 16);  // local row gg*4+r
        const uint2 h = *(const uint2*)&myslab[(gg * 4 + r) * LSTR + lane * 4];
        wacc[0] = fmaf(a_s, bflo(h.x), wacc[0]);
        wacc[1] = fmaf(a_s, bfhi(h.x), wacc[1]);
        wacc[2] = fmaf(a_s, bflo(h.y), wacc[2]);
        wacc[3] = fmaf(a_s, bfhi(h.y), wacc[3]);
      }
    }
  }

  // finish dacc: sum the 4 group values -> uniform across wave
  dacc += __shfl_xor(dacc, 16);
  dacc += __shfl_xor(dacc, 32);

  // block combine (slabs dead -> overlay), single end barrier pair
  __syncthreads();
  float* ldsW = (float*)slab;  // 257 floats
  if (t < 256) ldsW[t] = 0.f;
  if (t == 0) ldsW[256] = 0.f;
  __syncthreads();
#pragma unroll
  for (int j = 0; j < 4; ++j) atomicAdd(&ldsW[lane * 4 + j], wacc[j]);
  if (lane == 0) atomicAdd(&ldsW[256], dacc);
  __syncthreads();
  const int blk = b * 64 + sb;
  pw[(long)blk * D_ + t] = ldsW[t];
  if (t == 0) dpart[blk] = ldsW[256];
}

// ---- finalize: part 0 => reduce wsum + GEMV; parts 1..32 => att renorm ----
__global__ void finalize_k(const float* __restrict__ pw, const float* __restrict__ dpart,
                           const float* __restrict__ Wv, const float* __restrict__ bv,
                           float* __restrict__ out, float* __restrict__ att) {
  __shared__ float red[64];
  __shared__ float wl[D_];
  const int b = blockIdx.x, t = threadIdx.x, part = blockIdx.y;
  if (t < 64) red[t] = dpart[b * 64 + t];
  __syncthreads();
  if (t < 32) red[t] += red[t + 32];
  __syncthreads();
  if (t < 16) red[t] += red[t + 16];
  __syncthreads();
  if (t < 8) red[t] += red[t + 8];
  __syncthreads();
  if (t < 4) red[t] += red[t + 4];
  __syncthreads();
  if (t < 2) red[t] += red[t + 2];
  __syncthreads();
  if (t == 0) red[0] += red[1];
  __syncthreads();
  const float dn = red[0];
  if (part == 0) {
    float s0 = 0.f, s1 = 0.f, s2 = 0.f, s3 = 0.f;
    const float* p = pw + (long)b * 64 * D_ + t;
#pragma unroll 4
    for (int sb = 0; sb < 64; sb += 4) {  // coalesced 1KB per iter
      s0 += p[(sb + 0) * D_]; s1 += p[(sb + 1) * D_];
      s2 += p[(sb + 2) * D_]; s3 += p[(sb + 3) * D_];
    }
    wl[t] = (s0 + s1) + (s2 + s3);
    __syncthreads();
    const float4* wr = (const float4*)&Wv[t * D_];
    const float4* wv = (const float4*)wl;
    float d0 = 0.f, d1 = 0.f, d2 = 0.f, d3 = 0.f;
#pragma unroll 8
    for (int e = 0; e < 64; ++e) {
      const float4 a = wv[e], w4 = wr[e];
      d0 = fmaf(a.x, w4.x, d0); d1 = fmaf(a.y, w4.y, d1);
      d2 = fmaf(a.z, w4.z, d2); d3 = fmaf(a.w, w4.w, d3);
    }
    out[b * D_ + t] = ((d0 + d1) + (d2 + d3)) / dn + bv[t];
  } else {
    const float inv = 1.0f / dn;
    att[(long)b * S_ + (part - 1) * 256 + t] *= inv;
  }
}

extern "C" void kernel_launch(void* const* d_in, const int* in_sizes, int n_in,
                              void* d_out, int out_size, void* d_ws, size_t ws_size,
                              hipStream_t stream) {
  const float* x = (const float*)d_in[0];        // [16,8192,256]
  const int* mask = (const int*)d_in[1];         // [16,64,8192]
  const float* Wv = (const float*)d_in[2];
  const float* bv = (const float*)d_in[3];
  const float* Wk = (const float*)d_in[4];
  const float* bk = (const float*)d_in[5];
  const float* queries = (const float*)d_in[6];  // [64,256]

  char* ws = (char*)d_ws;
  u16* qf = (u16*)ws;                        // [0, 32768)  frag-ordered Q' bf16
  float* qb = (float*)(ws + 32768);          // [32768, 33792)
  float* pw = (float*)(ws + 33792);          // 1024 x 256 f32 partials (1MB)
  float* dpart = (float*)(ws + 33792 + 1048576);  // 1024 floats
  float* out = (float*)d_out;                // 16*256
  float* att = out + B_ * D_;                // 16*8192

  prep_qk<<<N_, D_, 0, stream>>>(queries, Wk, bk, qf, qb);
  attn_main<<<dim3(64, B_), 256, 0, stream>>>(x, mask, qf, qb, pw, dpart, att);
  finalize_k<<<dim3(B_, 33), 256, 0, stream>>>(pw, dpart, Wv, bv, out, att);
}